// Round 3
// baseline (1471.696 us; speedup 1.0000x reference)
//
#include <hip/hip_runtime.h>
#include <cstdint>
#include <cstddef>

typedef unsigned short u16;
typedef __attribute__((ext_vector_type(8))) short s8v;   // 8 bf16 in 4 VGPRs
typedef __attribute__((ext_vector_type(4))) float f4v;   // MFMA accumulator

#define D_MODEL 1024
#define D_INNER 2048
#define BT      8192   // B*T
#define TLEN    2048
#define NBATCH  4
#define QSLOT   512    // quad index slots per batch (power of 2 for addressing)
#define NQUAD   511    // actual quads per batch: t = 4q+1 .. 4q+4, q in [0,511)

struct alignas(8) U16x4 { u16 x, y, z, w; };

__device__ __forceinline__ u16 f2bf(float f) {
  union { float f; unsigned u; } c; c.f = f;
  unsigned r = c.u + 0x7FFFu + ((c.u >> 16) & 1u);   // RNE
  return (u16)(r >> 16);
}
// bf16 unpack from packed pair (u32): low ch / high ch
__device__ __forceinline__ float blo(unsigned u) {
  union { unsigned u; float f; } c; c.u = u << 16; return c.f;
}
__device__ __forceinline__ float bhi(unsigned u) {
  union { unsigned u; float f; } c; c.u = u & 0xffff0000u; return c.f;
}
// pack two fp32 -> packed bf16 pair (round half up), lo in low 16
__device__ __forceinline__ unsigned pkbf(float lo, float hi) {
  union { float f; unsigned u; } a, b; a.f = lo; b.f = hi;
#if __has_builtin(__builtin_amdgcn_perm)
  return __builtin_amdgcn_perm(b.u + 0x8000u, a.u + 0x8000u, 0x07060302u);
#else
  return ((b.u + 0x8000u) & 0xffff0000u) | ((a.u + 0x8000u) >> 16);
#endif
}

// DPP wave-64 sum: VALU-pipe latency instead of ds_bpermute. Result in lane 63.
#define DPPADD(x, ctrl) \
  ((x) + __builtin_bit_cast(float, __builtin_amdgcn_update_dpp( \
       0, __builtin_bit_cast(int, (x)), (ctrl), 0xF, 0xF, true)))
__device__ __forceinline__ float wave_sum_dpp(float x) {
  x = DPPADD(x, 0x111);  // row_shr:1
  x = DPPADD(x, 0x112);  // row_shr:2
  x = DPPADD(x, 0x114);  // row_shr:4
  x = DPPADD(x, 0x118);  // row_shr:8
  x = DPPADD(x, 0x142);  // row_bcast:15
  x = DPPADD(x, 0x143);  // row_bcast:31
  return x;              // lane 63 = wave sum
}

// async global->LDS, 16B per lane; LDS dest must be wave-uniform base (+lane*16 by HW)
__device__ __forceinline__ void glds16(const u16* g, const u16* lds) {
  __builtin_amdgcn_global_load_lds(
      (const __attribute__((address_space(1))) unsigned int*)(uintptr_t)g,
      (__attribute__((address_space(3))) unsigned int*)(unsigned int)(uintptr_t)lds,
      16, 0, 0);
}

// ---------------------------------------------------------------------------
// GEMM (unchanged)
// ---------------------------------------------------------------------------
template<int EPI>
__global__ __launch_bounds__(256, 2)
void gemm_nt(const u16* __restrict__ A, const u16* __restrict__ B,
             int M, int N, int K,
             float* __restrict__ Cf, u16* __restrict__ Cb, u16* __restrict__ Cb2,
             const float* __restrict__ bias, const float* __restrict__ sfac,
             const float* __restrict__ bias2)
{
  __shared__ u16 lA[128 * 32];
  __shared__ u16 lB[128 * 32];
  const int tid  = threadIdx.x;
  const int wave = tid >> 6, lane = tid & 63;
  const int wm = wave >> 1, wn = wave & 1;
  const int bm0 = blockIdx.y * 128, bn0 = blockIdx.x * 128;

  const int srow = lane >> 2;
  const int scol = (lane & 3) * 8;
  const u16* pa0 = A + (size_t)(bm0 + wave * 32 + srow) * K + scol;
  const u16* pa1 = pa0 + (size_t)16 * K;
  const u16* pb0 = B + (size_t)(bn0 + wave * 32 + srow) * K + scol;
  const u16* pb1 = pb0 + (size_t)16 * K;
  u16* la0 = lA + (wave * 32) * 32;
  u16* la1 = la0 + 16 * 32;
  u16* lb0 = lB + (wave * 32) * 32;
  u16* lb1 = lb0 + 16 * 32;

  const int fr = lane & 15, kq = lane >> 4;
  const u16* fA = lA + (wm * 64 + fr) * 32 + kq * 8;
  const u16* fB = lB + (wn * 64 + fr) * 32 + kq * 8;

  f4v acc[4][4];
  const f4v zf = {0.f, 0.f, 0.f, 0.f};
  for (int i = 0; i < 4; ++i)
    for (int j = 0; j < 4; ++j)
      acc[i][j] = zf;

  for (int k0 = 0; k0 < K; k0 += 32) {
    glds16(pa0 + k0, la0);
    glds16(pa1 + k0, la1);
    glds16(pb0 + k0, lb0);
    glds16(pb1 + k0, lb1);
    __syncthreads();
    s8v af[4], bfv[4];
#pragma unroll
    for (int i = 0; i < 4; ++i) af[i] = *(const s8v*)(fA + i * 16 * 32);
#pragma unroll
    for (int j = 0; j < 4; ++j) bfv[j] = *(const s8v*)(fB + j * 16 * 32);
#pragma unroll
    for (int i = 0; i < 4; ++i)
#pragma unroll
      for (int j = 0; j < 4; ++j)
        acc[i][j] = __builtin_amdgcn_mfma_f32_16x16x32_bf16(af[i], bfv[j], acc[i][j], 0, 0, 0);
    __syncthreads();
  }

  // C/D layout: col = lane&15, row = (lane>>4)*4 + reg
#pragma unroll
  for (int i = 0; i < 4; ++i) {
#pragma unroll
    for (int j = 0; j < 4; ++j) {
#pragma unroll
      for (int r = 0; r < 4; ++r) {
        const int gm = bm0 + wm * 64 + i * 16 + kq * 4 + r;
        const int gn = bn0 + wn * 64 + j * 16 + fr;
        const float val = acc[i][j][r];
        if (EPI == 0) {
          if (gn < D_INNER) {
            Cb[(size_t)gm * D_INNER + gn] = f2bf(val);
          } else {
            const float s = val / (1.f + __expf(-val));  // silu(z)
            Cb2[(size_t)gm * D_INNER + (gn - D_INNER)] = f2bf(s);
          }
        } else if (EPI == 4) {
          if (gn < D_INNER) {
            const float pre = val + bias[gn];
            const float sig = 1.f / (1.f + __expf(-pre));
            Cf[(size_t)gm * D_INNER + gn] = __expf(sfac[gn] * sig);
          } else {
            Cb[(size_t)gm * D_INNER + (gn - D_INNER)] = f2bf(val + bias2[gn - D_INNER]);
          }
        } else {
          Cf[(size_t)gm * N + gn] = val;
        }
      }
    }
  }
}

__global__ void conv_bf16_kernel(const float* __restrict__ in, u16* __restrict__ out, int n4)
{
  const int i = blockIdx.x * blockDim.x + threadIdx.x;
  if (i >= n4) return;
  const float4 x = ((const float4*)in)[i];
  U16x4 o; o.x = f2bf(x.x); o.y = f2bf(x.y); o.z = f2bf(x.z); o.w = f2bf(x.w);
  ((U16x4*)out)[i] = o;
}

__global__ void sfac_kernel(const float* __restrict__ omega, float* __restrict__ sfac)
{
  const int i = blockIdx.x * blockDim.x + threadIdx.x;
  if (i < D_INNER) sfac[i] = -8.f * log1pf(expf(omega[i]));  // -C*softplus(omega)
}

// v <- v * sqrt(2/(v.v)) per row; 1 wave per row, 4 rows per block.
__global__ __launch_bounds__(256)
void vscale_kernel(u16* __restrict__ v)
{
  const int row  = blockIdx.x * 4 + (threadIdx.x >> 6);
  const int lane = threadIdx.x & 63;
  uint4* p = (uint4*)(v + (size_t)row * D_INNER + lane * 32);  // 32 ch/lane
  uint4 a[4];
#pragma unroll
  for (int i = 0; i < 4; ++i) a[i] = p[i];
  float s = 0.f;
#pragma unroll
  for (int i = 0; i < 4; ++i) {
    const unsigned w[4] = {a[i].x, a[i].y, a[i].z, a[i].w};
#pragma unroll
    for (int j = 0; j < 4; ++j) {
      const float f0 = blo(w[j]), f1 = bhi(w[j]);
      s += f0 * f0 + f1 * f1;
    }
  }
  s += __shfl_down(s, 32); s += __shfl_down(s, 16); s += __shfl_down(s, 8);
  s += __shfl_down(s, 4);  s += __shfl_down(s, 2);  s += __shfl_down(s, 1);
  const float sc = sqrtf(2.f / __shfl(s, 0));
#pragma unroll
  for (int i = 0; i < 4; ++i) {
    const unsigned w[4] = {a[i].x, a[i].y, a[i].z, a[i].w};
    unsigned o[4];
#pragma unroll
    for (int j = 0; j < 4; ++j) o[j] = pkbf(blo(w[j]) * sc, bhi(w[j]) * sc);
    uint4 ov; ov.x = o[0]; ov.y = o[1]; ov.z = o[2]; ov.w = o[3];
    p[i] = ov;
  }
}

// ---------------------------------------------------------------------------
// Quad precompute (G=4 WY-style). Quad q of batch b covers t = 4q+1..4q+4.
// With s_j = v_j . h_{j-1} (the scan's dot scalars) and u_j = (1-l_j) x_j:
//   s_1 = v1.h0
//   s_2 = w2.h0 + d2 - c21 s1,         w2 = v2*l1
//   s_3 = w3.h0 + d3 - c31 s1 - c32 s2, w3 = v3*l2*l1
//   s_4 = w4.h0 + d4 - c41 s1 - c42 s2 - c43 s3, w4 = v4*l3*l2*l1
// where
//   c21 = w2.v1, c31 = w3.v1, c32 = (v3*l2).v2,
//   c41 = w4.v1, c42 = (v4*l3*l2).v2, c43 = (v4*l3).v3,
//   d2 = v2.u1, d3 = (v3*l2).u1 + v3.u2,
//   d4 = (v4*l3*l2).u1 + (v4*l3).u2 + v4.u3
// w2..w4 are stored bf16-ROUNDED; the c_j1 terms use the rounded values so
// the scan's algebra matches what it actually dots (pairprep discipline).
// One wave per quad, 32 ch/lane. Coef: cf[r*3+0] = {c21,c31,c32,c41},
// cf[r*3+1] = {c42,c43,d2,d3}, cf[r*3+2] = {d4,0,0,0}, r = b*QSLOT+q.
// ---------------------------------------------------------------------------
__global__ __launch_bounds__(256)
void quadprep_kernel(const u16* __restrict__ vs, const float* __restrict__ lam,
                     const u16* __restrict__ xi, u16* __restrict__ wq,
                     float4* __restrict__ cf)
{
  const int r = blockIdx.x * 4 + (threadIdx.x >> 6);
  const int lane = threadIdx.x & 63;
  const int b = r >> 9;              // QSLOT = 512
  const int q = r & (QSLOT - 1);
  if (q >= NQUAD) return;
  const int t0 = 4 * q + 1;
  const size_t e = ((size_t)b * TLEN + t0) * D_INNER + (size_t)lane * 32;
  u16* w2p = wq + ((size_t)r * 3 + 0) * D_INNER + (size_t)lane * 32;
  u16* w3p = wq + ((size_t)r * 3 + 1) * D_INNER + (size_t)lane * 32;
  u16* w4p = wq + ((size_t)r * 3 + 2) * D_INNER + (size_t)lane * 32;

  float c21 = 0, c31 = 0, c32 = 0, c41 = 0, c42 = 0, c43 = 0;
  float d2 = 0, d3 = 0, d4 = 0;

#pragma unroll
  for (int i = 0; i < 4; ++i) {
    const size_t o = e + i * 8;
    const uint4 v1 = *(const uint4*)(vs + o);
    const uint4 v2 = *(const uint4*)(vs + o + D_INNER);
    const uint4 v3 = *(const uint4*)(vs + o + 2 * D_INNER);
    const uint4 v4 = *(const uint4*)(vs + o + 3 * D_INNER);
    const uint4 x1 = *(const uint4*)(xi + o);
    const uint4 x2 = *(const uint4*)(xi + o + D_INNER);
    const uint4 x3 = *(const uint4*)(xi + o + 2 * D_INNER);
    const float4* l1p = (const float4*)(lam + o);
    const float4* l2p = (const float4*)(lam + o + D_INNER);
    const float4* l3p = (const float4*)(lam + o + 2 * D_INNER);
    const float4 l1a4 = l1p[0], l1b4 = l1p[1];
    const float4 l2a4 = l2p[0], l2b4 = l2p[1];
    const float4 l3a4 = l3p[0], l3b4 = l3p[1];
    const float lf1[8] = {l1a4.x, l1a4.y, l1a4.z, l1a4.w, l1b4.x, l1b4.y, l1b4.z, l1b4.w};
    const float lf2[8] = {l2a4.x, l2a4.y, l2a4.z, l2a4.w, l2b4.x, l2b4.y, l2b4.z, l2b4.w};
    const float lf3[8] = {l3a4.x, l3a4.y, l3a4.z, l3a4.w, l3b4.x, l3b4.y, l3b4.z, l3b4.w};
    const unsigned v1w[4] = {v1.x, v1.y, v1.z, v1.w};
    const unsigned v2w[4] = {v2.x, v2.y, v2.z, v2.w};
    const unsigned v3w[4] = {v3.x, v3.y, v3.z, v3.w};
    const unsigned v4w[4] = {v4.x, v4.y, v4.z, v4.w};
    const unsigned x1w[4] = {x1.x, x1.y, x1.z, x1.w};
    const unsigned x2w[4] = {x2.x, x2.y, x2.z, x2.w};
    const unsigned x3w[4] = {x3.x, x3.y, x3.z, x3.w};
    unsigned ow2[4], ow3[4], ow4[4];
#pragma unroll
    for (int k = 0; k < 4; ++k) {
      const float v1a = blo(v1w[k]), v1b = bhi(v1w[k]);
      const float v2a = blo(v2w[k]), v2b = bhi(v2w[k]);
      const float v3a = blo(v3w[k]), v3b = bhi(v3w[k]);
      const float v4a = blo(v4w[k]), v4b = bhi(v4w[k]);
      const float l1a = lf1[2*k], l1b = lf1[2*k+1];
      const float l2a = lf2[2*k], l2b = lf2[2*k+1];
      const float l3a = lf3[2*k], l3b = lf3[2*k+1];
      const float u1a = (1.f - l1a) * blo(x1w[k]), u1b = (1.f - l1b) * bhi(x1w[k]);
      const float u2a = (1.f - l2a) * blo(x2w[k]), u2b = (1.f - l2b) * bhi(x2w[k]);
      const float u3a = (1.f - l3a) * blo(x3w[k]), u3b = (1.f - l3b) * bhi(x3w[k]);
      // w2 = v2*l1
      const float p2a = v2a * l1a, p2b = v2b * l1b;
      ow2[k] = pkbf(p2a, p2b);
      c21 += blo(ow2[k]) * v1a + bhi(ow2[k]) * v1b;
      d2  += v2a * u1a + v2b * u1b;
      // p3 = v3*l2; w3 = p3*l1
      const float p3a = v3a * l2a, p3b = v3b * l2b;
      c32 += p3a * v2a + p3b * v2b;
      d3  += p3a * u1a + p3b * u1b + v3a * u2a + v3b * u2b;
      const float w3a = p3a * l1a, w3b = p3b * l1b;
      ow3[k] = pkbf(w3a, w3b);
      c31 += blo(ow3[k]) * v1a + bhi(ow3[k]) * v1b;
      // p4 = v4*l3; q4 = p4*l2; w4 = q4*l1
      const float p4a = v4a * l3a, p4b = v4b * l3b;
      c43 += p4a * v3a + p4b * v3b;
      const float q4a = p4a * l2a, q4b = p4b * l2b;
      c42 += q4a * v2a + q4b * v2b;
      d4  += q4a * u1a + q4b * u1b + p4a * u2a + p4b * u2b + v4a * u3a + v4b * u3b;
      const float w4a = q4a * l1a, w4b = q4b * l1b;
      ow4[k] = pkbf(w4a, w4b);
      c41 += blo(ow4[k]) * v1a + bhi(ow4[k]) * v1b;
    }
    uint4 s2; s2.x = ow2[0]; s2.y = ow2[1]; s2.z = ow2[2]; s2.w = ow2[3];
    uint4 s3; s3.x = ow3[0]; s3.y = ow3[1]; s3.z = ow3[2]; s3.w = ow3[3];
    uint4 s4; s4.x = ow4[0]; s4.y = ow4[1]; s4.z = ow4[2]; s4.w = ow4[3];
    *(uint4*)(w2p + i * 8) = s2;
    *(uint4*)(w3p + i * 8) = s3;
    *(uint4*)(w4p + i * 8) = s4;
  }
  c21 = wave_sum_dpp(c21); c31 = wave_sum_dpp(c31); c32 = wave_sum_dpp(c32);
  c41 = wave_sum_dpp(c41); c42 = wave_sum_dpp(c42); c43 = wave_sum_dpp(c43);
  d2 = wave_sum_dpp(d2); d3 = wave_sum_dpp(d3); d4 = wave_sum_dpp(d4);
  if (lane == 63) {
    float4 a; a.x = c21; a.y = c31; a.z = c32; a.w = c41;
    float4 bq; bq.x = c42; bq.y = c43; bq.z = d2; bq.w = d3;
    float4 cc; cc.x = d4; cc.y = 0.f; cc.z = 0.f; cc.w = 0.f;
    cf[(size_t)r * 3 + 0] = a;
    cf[(size_t)r * 3 + 1] = bq;
    cf[(size_t)r * 3 + 2] = cc;
  }
}

// ---------------------------------------------------------------------------
// Quad sequential scan: 512 threads (8 waves, 2/SIMD), 4 ch/thread.
// One barrier round per 4 timesteps (vs 2 previously); 2 waves/SIMD fill
// each other's dependency bubbles. Prefetch: separate-struct + sched_barrier
// (verified pattern from round 2).
// ---------------------------------------------------------------------------
struct Quad {
  uint2 w2, w3, w4;
  uint2 v1, v2, v3, v4;
  uint2 x1, x2, x3, x4;
  uint2 z1, z2, z3, z4;
  float4 l1, l2, l3, l4;
  float4 c0, c1, c2;
};

__global__ __launch_bounds__(512, 2)
void scan4_kernel(const u16* __restrict__ xi, const u16* __restrict__ sz,
                  const u16* __restrict__ vs, const float* __restrict__ lam,
                  const u16* __restrict__ wq, const float4* __restrict__ cf,
                  u16* __restrict__ gh)
{
  const int b = blockIdx.x, tid = threadIdx.x;
  const int wave = tid >> 6, lane = tid & 63;
  const size_t base = (size_t)b * TLEN * D_INNER + (size_t)tid * 4;
  __shared__ __attribute__((aligned(16))) float sS[2][4][8];

  auto load_quad = [&](int q) {
    Quad p;
    const size_t e1 = base + (size_t)(4 * q + 1) * D_INNER;
    p.v1 = *(const uint2*)(vs + e1);
    p.v2 = *(const uint2*)(vs + e1 + D_INNER);
    p.v3 = *(const uint2*)(vs + e1 + 2 * D_INNER);
    p.v4 = *(const uint2*)(vs + e1 + 3 * D_INNER);
    p.x1 = *(const uint2*)(xi + e1);
    p.x2 = *(const uint2*)(xi + e1 + D_INNER);
    p.x3 = *(const uint2*)(xi + e1 + 2 * D_INNER);
    p.x4 = *(const uint2*)(xi + e1 + 3 * D_INNER);
    p.z1 = *(const uint2*)(sz + e1);
    p.z2 = *(const uint2*)(sz + e1 + D_INNER);
    p.z3 = *(const uint2*)(sz + e1 + 2 * D_INNER);
    p.z4 = *(const uint2*)(sz + e1 + 3 * D_INNER);
    p.l1 = *(const float4*)(lam + e1);
    p.l2 = *(const float4*)(lam + e1 + D_INNER);
    p.l3 = *(const float4*)(lam + e1 + 2 * D_INNER);
    p.l4 = *(const float4*)(lam + e1 + 3 * D_INNER);
    const size_t wr = ((size_t)(b * QSLOT + q) * 3) * D_INNER + (size_t)tid * 4;
    p.w2 = *(const uint2*)(wq + wr);
    p.w3 = *(const uint2*)(wq + wr + D_INNER);
    p.w4 = *(const uint2*)(wq + wr + 2 * D_INNER);
    const float4* cp = cf + (size_t)(b * QSLOT + q) * 3;
    p.c0 = cp[0]; p.c1 = cp[1]; p.c2 = cp[2];
    return p;
  };

  float h[4];
  {  // t = 0: h = xi, gh = sz*h
    const uint2 x0 = *(const uint2*)(xi + base);
    const uint2 z0 = *(const uint2*)(sz + base);
    h[0] = blo(x0.x); h[1] = bhi(x0.x); h[2] = blo(x0.y); h[3] = bhi(x0.y);
    uint2 ov;
    ov.x = pkbf(blo(z0.x) * h[0], bhi(z0.x) * h[1]);
    ov.y = pkbf(blo(z0.y) * h[2], bhi(z0.y) * h[3]);
    *(uint2*)(gh + base) = ov;
  }

  // elementwise step: h <- l*(h - v*s - x) + x ; out = z*h
  auto step = [&](uint2 vv, float4 lv, uint2 xv, uint2 zv, float s, size_t off) {
    const float vf[4] = {blo(vv.x), bhi(vv.x), blo(vv.y), bhi(vv.y)};
    const float xf[4] = {blo(xv.x), bhi(xv.x), blo(xv.y), bhi(xv.y)};
    const float lf[4] = {lv.x, lv.y, lv.z, lv.w};
#pragma unroll
    for (int k = 0; k < 4; ++k) {
      const float t_ = __builtin_fmaf(vf[k], -s, h[k]);
      h[k] = __builtin_fmaf(lf[k], t_ - xf[k], xf[k]);
    }
    uint2 ov;
    ov.x = pkbf(blo(zv.x) * h[0], bhi(zv.x) * h[1]);
    ov.y = pkbf(blo(zv.y) * h[2], bhi(zv.y) * h[3]);
    *(uint2*)(gh + off) = ov;
  };

  auto round = [&](const Quad& p, int q) {
    const int par = q & 1;
    const float v1f[4] = {blo(p.v1.x), bhi(p.v1.x), blo(p.v1.y), bhi(p.v1.y)};
    const float w2f[4] = {blo(p.w2.x), bhi(p.w2.x), blo(p.w2.y), bhi(p.w2.y)};
    const float w3f[4] = {blo(p.w3.x), bhi(p.w3.x), blo(p.w3.y), bhi(p.w3.y)};
    const float w4f[4] = {blo(p.w4.x), bhi(p.w4.x), blo(p.w4.y), bhi(p.w4.y)};
    float P1 = 0.f, P2 = 0.f, P3 = 0.f, P4 = 0.f;
#pragma unroll
    for (int k = 0; k < 4; ++k) {
      P1 = __builtin_fmaf(v1f[k], h[k], P1);
      P2 = __builtin_fmaf(w2f[k], h[k], P2);
      P3 = __builtin_fmaf(w3f[k], h[k], P3);
      P4 = __builtin_fmaf(w4f[k], h[k], P4);
    }
    P1 = wave_sum_dpp(P1); P2 = wave_sum_dpp(P2);
    P3 = wave_sum_dpp(P3); P4 = wave_sum_dpp(P4);
    if (lane == 63) {
      sS[par][0][wave] = P1; sS[par][1][wave] = P2;
      sS[par][2][wave] = P3; sS[par][3][wave] = P4;
    }
    asm volatile("s_waitcnt lgkmcnt(0)\n\ts_barrier" ::: "memory");
    float S[4];
#pragma unroll
    for (int j = 0; j < 4; ++j) {
      const float4 pa = *(const float4*)&sS[par][j][0];
      const float4 pb = *(const float4*)&sS[par][j][4];
      S[j] = ((pa.x + pa.y) + (pa.z + pa.w)) + ((pb.x + pb.y) + (pb.z + pb.w));
    }
    const float c21 = p.c0.x, c31 = p.c0.y, c32 = p.c0.z, c41 = p.c0.w;
    const float c42 = p.c1.x, c43 = p.c1.y, d2 = p.c1.z, d3 = p.c1.w;
    const float d4 = p.c2.x;
    const float s1 = S[0];
    const float s2 = __builtin_fmaf(-c21, s1, S[1] + d2);
    const float s3 = __builtin_fmaf(-c32, s2, __builtin_fmaf(-c31, s1, S[2] + d3));
    const float s4 = __builtin_fmaf(-c43, s3,
                      __builtin_fmaf(-c42, s2, __builtin_fmaf(-c41, s1, S[3] + d4)));
    const size_t e1 = base + (size_t)(4 * q + 1) * D_INNER;
    step(p.v1, p.l1, p.x1, p.z1, s1, e1);
    step(p.v2, p.l2, p.x2, p.z2, s2, e1 + D_INNER);
    step(p.v3, p.l3, p.x3, p.z3, s3, e1 + 2 * D_INNER);
    step(p.v4, p.l4, p.x4, p.z4, s4, e1 + 3 * D_INNER);
  };

  // solo step for the 3-step tail (t = 2045..2047); par alternates 1,0,1 so
  // a slot is never rewritten with only one barrier since its last read
  auto solo = [&](int t, int par) {
    const size_t o = base + (size_t)t * D_INNER;
    const uint2 vv = *(const uint2*)(vs + o);
    const uint2 xv = *(const uint2*)(xi + o);
    const uint2 zv = *(const uint2*)(sz + o);
    const float4 lv = *(const float4*)(lam + o);
    const float vf[4] = {blo(vv.x), bhi(vv.x), blo(vv.y), bhi(vv.y)};
    float P = 0.f;
#pragma unroll
    for (int k = 0; k < 4; ++k) P = __builtin_fmaf(vf[k], h[k], P);
    P = wave_sum_dpp(P);
    if (lane == 63) sS[par][0][wave] = P;
    asm volatile("s_waitcnt lgkmcnt(0)\n\ts_barrier" ::: "memory");
    const float4 pa = *(const float4*)&sS[par][0][0];
    const float4 pb = *(const float4*)&sS[par][0][4];
    const float s = ((pa.x + pa.y) + (pa.z + pa.w)) + ((pb.x + pb.y) + (pb.z + pb.w));
    step(vv, lv, xv, zv, s, o);
  };

  // pipeline: depth-2 prefetch, sched_barrier pins issue points
  Quad A = load_quad(0);
  __builtin_amdgcn_sched_barrier(0);
  Quad B = load_quad(1);
  __builtin_amdgcn_sched_barrier(0);
  for (int q = 0; q <= 507; q += 2) {
    Quad An = load_quad(q + 2);
    __builtin_amdgcn_sched_barrier(0);
    round(A, q);
    A = An;
    Quad Bn = load_quad(q + 3);
    __builtin_amdgcn_sched_barrier(0);
    round(B, q + 1);
    B = Bn;
  }
  {
    Quad An = load_quad(510);
    __builtin_amdgcn_sched_barrier(0);
    round(A, 508);
    round(B, 509);
    round(An, 510);
  }
  solo(2045, 1);
  solo(2046, 0);
  solo(2047, 1);
}

extern "C" void kernel_launch(void* const* d_in, const int* in_sizes, int n_in,
                              void* d_out, int out_size, void* d_ws, size_t ws_size,
                              hipStream_t stream)
{
  const float* x     = (const float*)d_in[0];
  const float* omega = (const float*)d_in[1];
  const float* Win   = (const float*)d_in[2];
  const float* Wl    = (const float*)d_in[3];
  const float* bl    = (const float*)d_in[4];
  const float* Wv    = (const float*)d_in[5];
  const float* bv    = (const float*)d_in[6];
  const float* Wout  = (const float*)d_in[7];
  float* out = (float*)d_out;
  (void)in_sizes; (void)n_in; (void)out_size; (void)ws_size;

  size_t off = 0;
  auto carve = [&](size_t bytes) -> void* {
    void* r = (char*)d_ws + off;
    off += (bytes + 255) & ~(size_t)255;
    return r;
  };
  u16*  x_bf    = (u16*)carve((size_t)BT * D_MODEL * 2);          // dead after gemm<0>
  u16*  Win_bf  = (u16*)carve((size_t)2 * D_INNER * D_MODEL * 2); // dead after gemm<0>
  u16*  Wl_bf   = (u16*)carve((size_t)D_INNER * D_INNER * 2);
  u16*  Wv_bf   = (u16*)carve((size_t)D_INNER * D_INNER * 2);
  u16*  Wout_bf = (u16*)carve((size_t)D_MODEL * D_INNER * 2);
  u16*  xi_bf   = (u16*)carve((size_t)BT * D_INNER * 2);
  u16*  sz_bf   = (u16*)carve((size_t)BT * D_INNER * 2);
  u16*  v_bf    = (u16*)carve((size_t)BT * D_INNER * 2);
  u16*  gh_bf   = (u16*)carve((size_t)BT * D_INNER * 2);
  float* lam    = (float*)carve((size_t)BT * D_INNER * 4);        // fp32: precision
  float* sfac   = (float*)carve((size_t)D_INNER * 4);
  float4* cf    = (float4*)carve((size_t)NBATCH * QSLOT * 3 * 16);
  // w-quad region: x_bf (16.78MB) + Win_bf (8.39MB) are contiguous (both
  // 256-aligned sizes) and dead after gemm<0>; exactly 4*QSLOT*3 rows.
  u16*  wquad   = x_bf;

  conv_bf16_kernel<<<(BT * D_MODEL / 4 + 255) / 256, 256, 0, stream>>>(x, x_bf, BT * D_MODEL / 4);
  conv_bf16_kernel<<<(2 * D_INNER * D_MODEL / 4 + 255) / 256, 256, 0, stream>>>(Win, Win_bf, 2 * D_INNER * D_MODEL / 4);
  conv_bf16_kernel<<<(D_INNER * D_INNER / 4 + 255) / 256, 256, 0, stream>>>(Wl, Wl_bf, D_INNER * D_INNER / 4);
  conv_bf16_kernel<<<(D_INNER * D_INNER / 4 + 255) / 256, 256, 0, stream>>>(Wv, Wv_bf, D_INNER * D_INNER / 4);
  conv_bf16_kernel<<<(D_MODEL * D_INNER / 4 + 255) / 256, 256, 0, stream>>>(Wout, Wout_bf, D_MODEL * D_INNER / 4);
  sfac_kernel<<<(D_INNER + 255) / 256, 256, 0, stream>>>(omega, sfac);

  // xz = x @ Win^T  -> xi (bf16) | silu(z) (bf16)
  gemm_nt<0><<<dim3(4096 / 128, BT / 128), 256, 0, stream>>>(
      x_bf, Win_bf, BT, 4096, D_MODEL, nullptr, xi_bf, sz_bf, nullptr, nullptr, nullptr);
  // merged: lam = exp(sfac*sigmoid(xi@Wl^T+bl)) fp32 | v = xi@Wv^T+bv bf16
  gemm_nt<4><<<dim3(4096 / 128, BT / 128), 256, 0, stream>>>(
      xi_bf, Wl_bf, BT, 4096, D_INNER, lam, v_bf, nullptr, bl, sfac, bv);
  // v <- v*sqrt(2/(v.v))
  vscale_kernel<<<BT / 4, 256, 0, stream>>>(v_bf);
  // quad cross-terms: w2..w4 (bf16, into dead x_bf/Win_bf region), cf
  quadprep_kernel<<<NBATCH * QSLOT / 4, 256, 0, stream>>>(v_bf, lam, xi_bf, wquad, cf);
  // quad sequential scan -> gh = silu(z)*h (bf16)
  scan4_kernel<<<NBATCH, 512, 0, stream>>>(xi_bf, sz_bf, v_bf, lam, wquad, cf, gh_bf);
  // out = gh @ Wout^T (fp32)
  gemm_nt<3><<<dim3(D_MODEL / 128, BT / 128), 256, 0, stream>>>(
      gh_bf, Wout_bf, BT, D_MODEL, D_INNER, out, nullptr, nullptr, nullptr, nullptr, nullptr);
}

// Round 4
// 1087.689 us; speedup vs baseline: 1.3530x; 1.3530x over previous
//
#include <hip/hip_runtime.h>
#include <cstdint>
#include <cstddef>

typedef unsigned short u16;
typedef __attribute__((ext_vector_type(8))) short s8v;   // 8 bf16 in 4 VGPRs
typedef __attribute__((ext_vector_type(4))) float f4v;   // MFMA accumulator
typedef __attribute__((ext_vector_type(2))) float f32x2;

#define D_MODEL 1024
#define D_INNER 2048
#define BT      8192   // B*T
#define TLEN    2048
#define NBATCH  4

struct alignas(8) U16x4 { u16 x, y, z, w; };

__device__ __forceinline__ u16 f2bf(float f) {
  union { float f; unsigned u; } c; c.f = f;
  unsigned r = c.u + 0x7FFFu + ((c.u >> 16) & 1u);   // RNE
  return (u16)(r >> 16);
}
// bf16 unpack from packed pair (u32): low ch / high ch
__device__ __forceinline__ float blo(unsigned u) {
  union { unsigned u; float f; } c; c.u = u << 16; return c.f;
}
__device__ __forceinline__ float bhi(unsigned u) {
  union { unsigned u; float f; } c; c.u = u & 0xffff0000u; return c.f;
}
// pack two fp32 -> packed bf16 pair (round half up), lo in low 16
__device__ __forceinline__ unsigned pkbf(float lo, float hi) {
  union { float f; unsigned u; } a, b; a.f = lo; b.f = hi;
#if __has_builtin(__builtin_amdgcn_perm)
  return __builtin_amdgcn_perm(b.u + 0x8000u, a.u + 0x8000u, 0x07060302u);
#else
  return ((b.u + 0x8000u) & 0xffff0000u) | ((a.u + 0x8000u) >> 16);
#endif
}

// DPP wave-64 sum: VALU-pipe latency instead of ds_bpermute. Result in lane 63.
#define DPPADD(x, ctrl) \
  ((x) + __builtin_bit_cast(float, __builtin_amdgcn_update_dpp( \
       0, __builtin_bit_cast(int, (x)), (ctrl), 0xF, 0xF, true)))
__device__ __forceinline__ float wave_sum_dpp(float x) {
  x = DPPADD(x, 0x111);  // row_shr:1
  x = DPPADD(x, 0x112);  // row_shr:2
  x = DPPADD(x, 0x114);  // row_shr:4
  x = DPPADD(x, 0x118);  // row_shr:8
  x = DPPADD(x, 0x142);  // row_bcast:15
  x = DPPADD(x, 0x143);  // row_bcast:31
  return x;              // lane 63 = wave sum
}

// async global->LDS, 16B per lane; LDS dest must be wave-uniform base (+lane*16 by HW)
__device__ __forceinline__ void glds16(const u16* g, const u16* lds) {
  __builtin_amdgcn_global_load_lds(
      (const __attribute__((address_space(1))) unsigned int*)(uintptr_t)g,
      (__attribute__((address_space(3))) unsigned int*)(unsigned int)(uintptr_t)lds,
      16, 0, 0);
}

// ---------------------------------------------------------------------------
// GEMM. EPI 0: split N=4096 -> Cb=xi bf16 | Cb2=silu(z) bf16
//       EPI 4: n<2048 -> Cb2 = bf16(1-lam) = bf16(-expm1(sfac*sigmoid(acc+bias)))
//              n>=2048 -> Cb = bf16(acc + bias2)   (v bf16)
//       EPI 3: Cf = acc (final out, fp32)
// ---------------------------------------------------------------------------
template<int EPI>
__global__ __launch_bounds__(256, 2)
void gemm_nt(const u16* __restrict__ A, const u16* __restrict__ B,
             int M, int N, int K,
             float* __restrict__ Cf, u16* __restrict__ Cb, u16* __restrict__ Cb2,
             const float* __restrict__ bias, const float* __restrict__ sfac,
             const float* __restrict__ bias2)
{
  __shared__ u16 lA[128 * 32];
  __shared__ u16 lB[128 * 32];
  const int tid  = threadIdx.x;
  const int wave = tid >> 6, lane = tid & 63;
  const int wm = wave >> 1, wn = wave & 1;
  const int bm0 = blockIdx.y * 128, bn0 = blockIdx.x * 128;

  const int srow = lane >> 2;
  const int scol = (lane & 3) * 8;
  const u16* pa0 = A + (size_t)(bm0 + wave * 32 + srow) * K + scol;
  const u16* pa1 = pa0 + (size_t)16 * K;
  const u16* pb0 = B + (size_t)(bn0 + wave * 32 + srow) * K + scol;
  const u16* pb1 = pb0 + (size_t)16 * K;
  u16* la0 = lA + (wave * 32) * 32;
  u16* la1 = la0 + 16 * 32;
  u16* lb0 = lB + (wave * 32) * 32;
  u16* lb1 = lb0 + 16 * 32;

  const int fr = lane & 15, kq = lane >> 4;
  const u16* fA = lA + (wm * 64 + fr) * 32 + kq * 8;
  const u16* fB = lB + (wn * 64 + fr) * 32 + kq * 8;

  f4v acc[4][4];
  const f4v zf = {0.f, 0.f, 0.f, 0.f};
  for (int i = 0; i < 4; ++i)
    for (int j = 0; j < 4; ++j)
      acc[i][j] = zf;

  for (int k0 = 0; k0 < K; k0 += 32) {
    glds16(pa0 + k0, la0);
    glds16(pa1 + k0, la1);
    glds16(pb0 + k0, lb0);
    glds16(pb1 + k0, lb1);
    __syncthreads();
    s8v af[4], bfv[4];
#pragma unroll
    for (int i = 0; i < 4; ++i) af[i] = *(const s8v*)(fA + i * 16 * 32);
#pragma unroll
    for (int j = 0; j < 4; ++j) bfv[j] = *(const s8v*)(fB + j * 16 * 32);
#pragma unroll
    for (int i = 0; i < 4; ++i)
#pragma unroll
      for (int j = 0; j < 4; ++j)
        acc[i][j] = __builtin_amdgcn_mfma_f32_16x16x32_bf16(af[i], bfv[j], acc[i][j], 0, 0, 0);
    __syncthreads();
  }

  // C/D layout: col = lane&15, row = (lane>>4)*4 + reg
#pragma unroll
  for (int i = 0; i < 4; ++i) {
#pragma unroll
    for (int j = 0; j < 4; ++j) {
#pragma unroll
      for (int r = 0; r < 4; ++r) {
        const int gm = bm0 + wm * 64 + i * 16 + kq * 4 + r;
        const int gn = bn0 + wn * 64 + j * 16 + fr;
        const float val = acc[i][j][r];
        if (EPI == 0) {
          if (gn < D_INNER) {
            Cb[(size_t)gm * D_INNER + gn] = f2bf(val);
          } else {
            const float s = val / (1.f + __expf(-val));  // silu(z)
            Cb2[(size_t)gm * D_INNER + (gn - D_INNER)] = f2bf(s);
          }
        } else if (EPI == 4) {
          if (gn < D_INNER) {
            const float pre = val + bias[gn];
            const float sig = 1.f / (1.f + __expf(-pre));
            const float m = -expm1f(sfac[gn] * sig);   // 1 - lam, full precision
            Cb2[(size_t)gm * D_INNER + gn] = f2bf(m);
          } else {
            Cb[(size_t)gm * D_INNER + (gn - D_INNER)] = f2bf(val + bias2[gn - D_INNER]);
          }
        } else {
          Cf[(size_t)gm * N + gn] = val;
        }
      }
    }
  }
}

__global__ void conv_bf16_kernel(const float* __restrict__ in, u16* __restrict__ out, int n4)
{
  const int i = blockIdx.x * blockDim.x + threadIdx.x;
  if (i >= n4) return;
  const float4 x = ((const float4*)in)[i];
  U16x4 o; o.x = f2bf(x.x); o.y = f2bf(x.y); o.z = f2bf(x.z); o.w = f2bf(x.w);
  ((U16x4*)out)[i] = o;
}

__global__ void sfac_kernel(const float* __restrict__ omega, float* __restrict__ sfac)
{
  const int i = blockIdx.x * blockDim.x + threadIdx.x;
  if (i < D_INNER) sfac[i] = -8.f * log1pf(expf(omega[i]));  // -C*softplus(omega)
}

// v <- v * sqrt(2/(v.v)) per row; 1 wave per row, 4 rows per block.
__global__ __launch_bounds__(256)
void vscale_kernel(u16* __restrict__ v)
{
  const int row  = blockIdx.x * 4 + (threadIdx.x >> 6);
  const int lane = threadIdx.x & 63;
  uint4* p = (uint4*)(v + (size_t)row * D_INNER + lane * 32);  // 32 ch/lane
  uint4 a[4];
#pragma unroll
  for (int i = 0; i < 4; ++i) a[i] = p[i];
  float s = 0.f;
#pragma unroll
  for (int i = 0; i < 4; ++i) {
    const unsigned w[4] = {a[i].x, a[i].y, a[i].z, a[i].w};
#pragma unroll
    for (int j = 0; j < 4; ++j) {
      const float f0 = blo(w[j]), f1 = bhi(w[j]);
      s += f0 * f0 + f1 * f1;
    }
  }
  s += __shfl_down(s, 32); s += __shfl_down(s, 16); s += __shfl_down(s, 8);
  s += __shfl_down(s, 4);  s += __shfl_down(s, 2);  s += __shfl_down(s, 1);
  const float sc = sqrtf(2.f / __shfl(s, 0));
#pragma unroll
  for (int i = 0; i < 4; ++i) {
    const unsigned w[4] = {a[i].x, a[i].y, a[i].z, a[i].w};
    unsigned o[4];
#pragma unroll
    for (int j = 0; j < 4; ++j) o[j] = pkbf(blo(w[j]) * sc, bhi(w[j]) * sc);
    uint4 ov; ov.x = o[0]; ov.y = o[1]; ov.z = o[2]; ov.w = o[3];
    p[i] = ov;
  }
}

// Pair precompute, one wave per even t. No w output (scan recomputes w
// in-register from v1,m0 with the SAME fp32 expression -> algebra exact):
//   C1_t = (v_{t+1} - v_{t+1}*m_t) . v_t
//   C2_t = v_{t+1} . (m_t * x_t)
__global__ __launch_bounds__(256)
void pairprep_kernel(const u16* __restrict__ vs, const u16* __restrict__ mb,
                     const u16* __restrict__ xi, f32x2* __restrict__ C12)
{
  const int r = blockIdx.x * 4 + (threadIdx.x >> 6);  // r = b*1024 + t/2
  const int lane = threadIdx.x & 63;
  const int b = r >> 10;
  const int t = (r & 1023) * 2;
  const size_t o0 = ((size_t)b * TLEN + t) * D_INNER + (size_t)lane * 32;
  const size_t o1 = o0 + D_INNER;
  const uint4* pv0 = (const uint4*)(vs + o0);
  const uint4* pv1 = (const uint4*)(vs + o1);
  const uint4* px0 = (const uint4*)(xi + o0);
  const uint4* pm0 = (const uint4*)(mb + o0);
  float c1 = 0.f, c2 = 0.f;
#pragma unroll
  for (int i = 0; i < 4; ++i) {
    const uint4 v0 = pv0[i], v1 = pv1[i], x0 = px0[i], m0 = pm0[i];
    const unsigned v0w[4] = {v0.x, v0.y, v0.z, v0.w};
    const unsigned v1w[4] = {v1.x, v1.y, v1.z, v1.w};
    const unsigned x0w[4] = {x0.x, x0.y, x0.z, x0.w};
    const unsigned m0w[4] = {m0.x, m0.y, m0.z, m0.w};
#pragma unroll
    for (int q = 0; q < 4; ++q) {
      const float va = blo(v0w[q]), vb = bhi(v0w[q]);
      const float ua = blo(v1w[q]), ub = bhi(v1w[q]);
      const float xa = blo(x0w[q]), xb = bhi(x0w[q]);
      const float ma = blo(m0w[q]), mbv = bhi(m0w[q]);
      const float wa = __builtin_fmaf(-ua, ma, ua);    // v1*(1-m0), fp32
      const float wb = __builtin_fmaf(-ub, mbv, ub);
      c1 += wa * va + wb * vb;
      c2 += ua * (ma * xa) + ub * (mbv * xb);
    }
  }
  c1 = wave_sum_dpp(c1);
  c2 = wave_sum_dpp(c2);
  if (lane == 63) { f32x2 cc; cc.x = c1; cc.y = c2; C12[r] = cc; }
}

// gh <- sz * gh  elementwise (full chip), in-place over the h buffer
__global__ void zmul_kernel(u16* __restrict__ gh, const u16* __restrict__ sz, int n8)
{
  const int i = blockIdx.x * blockDim.x + threadIdx.x;
  if (i >= n8) return;
  const uint4 hv = ((const uint4*)gh)[i];
  const uint4 zv = ((const uint4*)sz)[i];
  const unsigned hw[4] = {hv.x, hv.y, hv.z, hv.w};
  const unsigned zw[4] = {zv.x, zv.y, zv.z, zv.w};
  unsigned ow[4];
#pragma unroll
  for (int q = 0; q < 4; ++q)
    ow[q] = pkbf(blo(zw[q]) * blo(hw[q]), bhi(zw[q]) * bhi(hw[q]));
  uint4 o; o.x = ow[0]; o.y = ow[1]; o.z = ow[2]; o.w = ow[3];
  ((uint4*)gh)[i] = o;
}

// ---------------------------------------------------------------------------
// Paired sequential scan — round-2 verified structure (256 thr, separate-
// struct prefetch + sched_barrier pins), on a traffic diet:
//   per round reads: v0,v1,x0,x1 (bf16) + m0,m1 (bf16, = 1-lam) + C12
//   = 104 B/thread vs 184 before. Scan is per-CU streaming-bound
//   (~25 B/cy/CU measured across two structures), so time ~ bytes.
// z is NOT read here; scan writes raw h, zmul applies the gate full-chip.
// w is recomputed in-register: w = fma(-v1, m0, v1)  (= v_{t+1} * l_t).
// Step: t0 = fma(v,-a,h); h = fma(m, x - t0, t0).
// ---------------------------------------------------------------------------
struct Pair {
  uint4 v0, v1, x0, x1, m0, m1;
  f32x2 c;
};

__global__ __launch_bounds__(256, 1)
void scan2_kernel(const u16* __restrict__ xi, const u16* __restrict__ vs,
                  const u16* __restrict__ mb, const f32x2* __restrict__ C12,
                  u16* __restrict__ hb)
{
  const int b = blockIdx.x, tid = threadIdx.x;
  const int wave = tid >> 6, lane = tid & 63;
  const size_t base = (size_t)b * TLEN * D_INNER + (size_t)tid * 8;
  const int cb0 = b * 1024;
  __shared__ __attribute__((aligned(16))) float rP[2][4], rQ[2][4];

  auto load_pair = [&](int t) {
    Pair p;
    const size_t o0 = base + (size_t)t * D_INNER;
    const size_t o1 = o0 + D_INNER;
    p.v0 = *(const uint4*)(vs + o0);
    p.v1 = *(const uint4*)(vs + o1);
    p.x0 = *(const uint4*)(xi + o0);
    p.x1 = *(const uint4*)(xi + o1);
    p.m0 = *(const uint4*)(mb + o0);
    p.m1 = *(const uint4*)(mb + o1);
    p.c = C12[cb0 + (t >> 1)];
    return p;
  };

  float h[8];
  {  // t = 0: h = xi (exact copy of bf16 row into h buffer)
    const uint4 x0 = *(const uint4*)(xi + base);
    const unsigned xw[4] = {x0.x, x0.y, x0.z, x0.w};
#pragma unroll
    for (int p = 0; p < 4; ++p) {
      h[2*p]   = blo(xw[p]);
      h[2*p+1] = bhi(xw[p]);
    }
    *(uint4*)(hb + base) = x0;
  }

  {  // solo step t = 1
    const size_t o = base + D_INNER;
    const uint4 v1v = *(const uint4*)(vs + o);
    const uint4 x1v = *(const uint4*)(xi + o);
    const uint4 m1v = *(const uint4*)(mb + o);
    const unsigned vw[4] = {v1v.x, v1v.y, v1v.z, v1v.w};
    float vf[8];
    float P0 = 0.f, P1 = 0.f;
#pragma unroll
    for (int p = 0; p < 4; ++p) {
      vf[2*p]   = blo(vw[p]);
      vf[2*p+1] = bhi(vw[p]);
      P0 = __builtin_fmaf(vf[2*p],   h[2*p],   P0);
      P1 = __builtin_fmaf(vf[2*p+1], h[2*p+1], P1);
    }
    float P = wave_sum_dpp(P0 + P1);
    if (lane == 63) rP[0][wave] = P;
    asm volatile("s_waitcnt lgkmcnt(0)\n\ts_barrier" ::: "memory");
    const float4 sp = *(const float4*)rP[0];
    const float a = (sp.x + sp.y) + (sp.z + sp.w);
    const unsigned xw[4] = {x1v.x, x1v.y, x1v.z, x1v.w};
    const unsigned mw[4] = {m1v.x, m1v.y, m1v.z, m1v.w};
    unsigned ow[4];
#pragma unroll
    for (int p = 0; p < 4; ++p) {
      const float X0 = blo(xw[p]), X1 = bhi(xw[p]);
      const float M0 = blo(mw[p]), M1 = bhi(mw[p]);
      const float t0 = __builtin_fmaf(vf[2*p],   -a, h[2*p]);
      const float t1 = __builtin_fmaf(vf[2*p+1], -a, h[2*p+1]);
      h[2*p]   = __builtin_fmaf(M0, X0 - t0, t0);
      h[2*p+1] = __builtin_fmaf(M1, X1 - t1, t1);
      ow[p] = pkbf(h[2*p], h[2*p+1]);
    }
    uint4 out; out.x = ow[0]; out.y = ow[1]; out.z = ow[2]; out.w = ow[3];
    *(uint4*)(hb + o) = out;
  }

  auto round = [&](const Pair& p, int t) {
    const int par = (t >> 1) & 1;
    const unsigned v0w[4] = {p.v0.x, p.v0.y, p.v0.z, p.v0.w};
    const unsigned v1w[4] = {p.v1.x, p.v1.y, p.v1.z, p.v1.w};
    const unsigned m0w[4] = {p.m0.x, p.m0.y, p.m0.z, p.m0.w};
    float vf[8], uf[8], mf0[8];
    float P0 = 0.f, P1 = 0.f, Q0 = 0.f, Q1 = 0.f;
#pragma unroll
    for (int q = 0; q < 4; ++q) {
      vf[2*q]   = blo(v0w[q]);
      vf[2*q+1] = bhi(v0w[q]);
      uf[2*q]   = blo(v1w[q]);
      uf[2*q+1] = bhi(v1w[q]);
      mf0[2*q]  = blo(m0w[q]);
      mf0[2*q+1]= bhi(m0w[q]);
      const float wa = __builtin_fmaf(-uf[2*q],   mf0[2*q],   uf[2*q]);   // v1*l0
      const float wb = __builtin_fmaf(-uf[2*q+1], mf0[2*q+1], uf[2*q+1]);
      P0 = __builtin_fmaf(vf[2*q],   h[2*q],   P0);
      P1 = __builtin_fmaf(vf[2*q+1], h[2*q+1], P1);
      Q0 = __builtin_fmaf(wa, h[2*q],   Q0);
      Q1 = __builtin_fmaf(wb, h[2*q+1], Q1);
    }
    float P = wave_sum_dpp(P0 + P1);
    float Q = wave_sum_dpp(Q0 + Q1);
    if (lane == 63) { rP[par][wave] = P; rQ[par][wave] = Q; }
    asm volatile("s_waitcnt lgkmcnt(0)\n\ts_barrier" ::: "memory");
    const float4 sp = *(const float4*)rP[par];
    const float4 sq = *(const float4*)rQ[par];
    const float a0 = (sp.x + sp.y) + (sp.z + sp.w);
    const float a1 = __builtin_fmaf(-a0, p.c.x, (sq.x + sq.y) + (sq.z + sq.w) + p.c.y);
    const unsigned xw0[4] = {p.x0.x, p.x0.y, p.x0.z, p.x0.w};
    const unsigned xw1[4] = {p.x1.x, p.x1.y, p.x1.z, p.x1.w};
    const unsigned m1w[4] = {p.m1.x, p.m1.y, p.m1.z, p.m1.w};
    unsigned ow0[4], ow1[4];
#pragma unroll
    for (int q = 0; q < 4; ++q) {
      const float A0 = blo(xw0[q]), A1 = bhi(xw0[q]);
      const float B0 = blo(xw1[q]), B1 = bhi(xw1[q]);
      const float N0 = blo(m1w[q]), N1 = bhi(m1w[q]);
      float t0 = __builtin_fmaf(vf[2*q],   -a0, h[2*q]);
      float t1 = __builtin_fmaf(vf[2*q+1], -a0, h[2*q+1]);
      t0 = __builtin_fmaf(mf0[2*q],   A0 - t0, t0);   // h_t
      t1 = __builtin_fmaf(mf0[2*q+1], A1 - t1, t1);
      ow0[q] = pkbf(t0, t1);
      const float u0 = __builtin_fmaf(uf[2*q],   -a1, t0);
      const float u1 = __builtin_fmaf(uf[2*q+1], -a1, t1);
      h[2*q]   = __builtin_fmaf(N0, B0 - u0, u0);     // h_{t+1}
      h[2*q+1] = __builtin_fmaf(N1, B1 - u1, u1);
      ow1[q] = pkbf(h[2*q], h[2*q+1]);
    }
    const size_t oo = base + (size_t)t * D_INNER;
    uint4 o0; o0.x = ow0[0]; o0.y = ow0[1]; o0.z = ow0[2]; o0.w = ow0[3];
    uint4 o1; o1.x = ow1[0]; o1.y = ow1[1]; o1.z = ow1[2]; o1.w = ow1[3];
    *(uint4*)(hb + oo) = o0;
    *(uint4*)(hb + oo + D_INNER) = o1;
  };

  // Software pipeline, depth = 2 rounds; sched_barrier(0) pins load clumps.
  Pair A = load_pair(2);
  __builtin_amdgcn_sched_barrier(0);
  Pair B = load_pair(4);
  __builtin_amdgcn_sched_barrier(0);
  for (int t = 2; t <= 2038; t += 4) {
    Pair An = load_pair(t + 4);
    __builtin_amdgcn_sched_barrier(0);
    round(A, t);
    A = An;
    Pair Bn = load_pair(t + 6);
    __builtin_amdgcn_sched_barrier(0);
    round(B, t + 2);
    B = Bn;
  }
  {
    Pair An = load_pair(2046);
    __builtin_amdgcn_sched_barrier(0);
    round(A, 2042);
    round(B, 2044);
    round(An, 2046);
  }
}

extern "C" void kernel_launch(void* const* d_in, const int* in_sizes, int n_in,
                              void* d_out, int out_size, void* d_ws, size_t ws_size,
                              hipStream_t stream)
{
  const float* x     = (const float*)d_in[0];
  const float* omega = (const float*)d_in[1];
  const float* Win   = (const float*)d_in[2];
  const float* Wl    = (const float*)d_in[3];
  const float* bl    = (const float*)d_in[4];
  const float* Wv    = (const float*)d_in[5];
  const float* bv    = (const float*)d_in[6];
  const float* Wout  = (const float*)d_in[7];
  float* out = (float*)d_out;
  (void)in_sizes; (void)n_in; (void)out_size; (void)ws_size;

  size_t off = 0;
  auto carve = [&](size_t bytes) -> void* {
    void* r = (char*)d_ws + off;
    off += (bytes + 255) & ~(size_t)255;
    return r;
  };
  u16*  x_bf    = (u16*)carve((size_t)BT * D_MODEL * 2);          // dead after gemm<0>
  u16*  Win_bf  = (u16*)carve((size_t)2 * D_INNER * D_MODEL * 2);
  u16*  Wl_bf   = (u16*)carve((size_t)D_INNER * D_INNER * 2);
  u16*  Wv_bf   = (u16*)carve((size_t)D_INNER * D_INNER * 2);
  u16*  Wout_bf = (u16*)carve((size_t)D_MODEL * D_INNER * 2);
  u16*  xi_bf   = (u16*)carve((size_t)BT * D_INNER * 2);
  u16*  sz_bf   = (u16*)carve((size_t)BT * D_INNER * 2);
  u16*  v_bf    = (u16*)carve((size_t)BT * D_INNER * 2);
  u16*  gh_bf   = (u16*)carve((size_t)BT * D_INNER * 2);   // scan h, then z*h in-place
  u16*  mb      = (u16*)carve((size_t)BT * D_INNER * 2);   // 1-lam, bf16
  float* sfac   = (float*)carve((size_t)D_INNER * 4);
  f32x2* C12    = (f32x2*)carve((size_t)(BT / 2) * 8);

  conv_bf16_kernel<<<(BT * D_MODEL / 4 + 255) / 256, 256, 0, stream>>>(x, x_bf, BT * D_MODEL / 4);
  conv_bf16_kernel<<<(2 * D_INNER * D_MODEL / 4 + 255) / 256, 256, 0, stream>>>(Win, Win_bf, 2 * D_INNER * D_MODEL / 4);
  conv_bf16_kernel<<<(D_INNER * D_INNER / 4 + 255) / 256, 256, 0, stream>>>(Wl, Wl_bf, D_INNER * D_INNER / 4);
  conv_bf16_kernel<<<(D_INNER * D_INNER / 4 + 255) / 256, 256, 0, stream>>>(Wv, Wv_bf, D_INNER * D_INNER / 4);
  conv_bf16_kernel<<<(D_MODEL * D_INNER / 4 + 255) / 256, 256, 0, stream>>>(Wout, Wout_bf, D_MODEL * D_INNER / 4);
  sfac_kernel<<<(D_INNER + 255) / 256, 256, 0, stream>>>(omega, sfac);

  // xz = x @ Win^T  -> xi (bf16) | silu(z) (bf16)
  gemm_nt<0><<<dim3(4096 / 128, BT / 128), 256, 0, stream>>>(
      x_bf, Win_bf, BT, 4096, D_MODEL, nullptr, xi_bf, sz_bf, nullptr, nullptr, nullptr);
  // merged: mb = bf16(1-lam) | v = xi@Wv^T+bv bf16
  gemm_nt<4><<<dim3(4096 / 128, BT / 128), 256, 0, stream>>>(
      xi_bf, Wl_bf, BT, 4096, D_INNER, nullptr, v_bf, mb, bl, sfac, bv);
  // v <- v*sqrt(2/(v.v))
  vscale_kernel<<<BT / 4, 256, 0, stream>>>(v_bf);
  // pair cross-terms: C12 = (C1,C2)
  pairprep_kernel<<<BT / 2 / 4, 256, 0, stream>>>(v_bf, mb, xi_bf, C12);
  // paired sequential scan -> hb = h (bf16)
  scan2_kernel<<<NBATCH, 256, 0, stream>>>(xi_bf, v_bf, mb, C12, gh_bf);
  // gh = silu(z)*h (full chip, in-place)
  zmul_kernel<<<(BT * D_INNER / 8 + 255) / 256, 256, 0, stream>>>(gh_bf, sz_bf, BT * D_INNER / 8);
  // out = gh @ Wout^T (fp32)
  gemm_nt<3><<<dim3(D_MODEL / 128, BT / 128), 256, 0, stream>>>(
      gh_bf, Wout_bf, BT, D_MODEL, D_INNER, out, nullptr, nullptr, nullptr, nullptr, nullptr);
}